// Round 1
// baseline (212.643 us; speedup 1.0000x reference)
//
#include <hip/hip_runtime.h>

#define BB 8
#define TT 256
#define UU 64
#define VV 512
#define U1 (UU + 1)

__device__ __forceinline__ float logadd(float a, float b) {
    float m = fmaxf(a, b);
    float d = fabsf(a - b);
    return m + __logf(1.0f + __expf(-d));
}

// Kernel 1: per-row log-softmax; extract blank lp and target (emit) lp.
// One wave (64 lanes) per row of 512 floats. Lane l holds elems [4l,4l+4) and [256+4l, 256+4l+4).
__global__ __launch_bounds__(256) void k_logsm(const float* __restrict__ logits,
                                               const int* __restrict__ targets,
                                               float* __restrict__ blank,
                                               float* __restrict__ emit) {
    int wave = (int)((blockIdx.x * blockDim.x + threadIdx.x) >> 6);
    int lane = threadIdx.x & 63;
    const int nrows = BB * TT * U1;
    if (wave >= nrows) return;
    const float* row = logits + (size_t)wave * VV;
    float4 v0 = *(const float4*)(row + lane * 4);
    float4 v1 = *(const float4*)(row + 256 + lane * 4);
    float m = fmaxf(fmaxf(fmaxf(v0.x, v0.y), fmaxf(v0.z, v0.w)),
                    fmaxf(fmaxf(v1.x, v1.y), fmaxf(v1.z, v1.w)));
    #pragma unroll
    for (int off = 32; off; off >>= 1) m = fmaxf(m, __shfl_xor(m, off));
    float s = __expf(v0.x - m) + __expf(v0.y - m) + __expf(v0.z - m) + __expf(v0.w - m)
            + __expf(v1.x - m) + __expf(v1.y - m) + __expf(v1.z - m) + __expf(v1.w - m);
    #pragma unroll
    for (int off = 32; off; off >>= 1) s += __shfl_xor(s, off);
    float lse = m + __logf(s);

    int u  = wave % U1;
    int bt = wave / U1;
    if (lane == 0) blank[wave] = v0.x - lse;
    if (u < UU) {
        int b = bt / TT;
        int tgt = targets[b * UU + u];           // in [1, V)
        int owner = (tgt & 255) >> 2;
        if (lane == owner) {
            int slot = tgt & 3;
            float x0 = (tgt < 256) ? v0.x : v1.x;
            float x1 = (tgt < 256) ? v0.y : v1.y;
            float x2 = (tgt < 256) ? v0.z : v1.z;
            float x3 = (tgt < 256) ? v0.w : v1.w;
            float val = (slot == 0) ? x0 : (slot == 1) ? x1 : (slot == 2) ? x2 : x3;
            emit[bt * UU + u] = val - lse;
        }
    }
}

// Kernel 2: cum_emit[b,t,0]=0 ; cum_emit[b,t,u]=sum_{j<u} emit[b,t,j]. One wave per (b,t).
__global__ __launch_bounds__(256) void k_cum(const float* __restrict__ emit,
                                             float* __restrict__ cum) {
    int wave = (int)((blockIdx.x * blockDim.x + threadIdx.x) >> 6);
    int lane = threadIdx.x & 63;
    const int nrows = BB * TT;
    if (wave >= nrows) return;
    float v = emit[wave * UU + lane];
    #pragma unroll
    for (int off = 1; off < 64; off <<= 1) {
        float o = __shfl_up(v, off);
        if (lane >= off) v += o;
    }
    cum[wave * U1 + lane + 1] = v;
    if (lane == 0) cum[wave * U1] = 0.f;
}

// Kernel 3: per-batch sequential alpha recursion. One wave per batch.
// Lane l owns u = l+1; u=0 tracked as scalar a0 (cum_emit[...,0] == 0).
__global__ __launch_bounds__(64) void k_scan(const float* __restrict__ blank,
                                             const float* __restrict__ cum,
                                             const int* __restrict__ loglen,
                                             const int* __restrict__ tgtlen,
                                             float* __restrict__ costs) {
    int b = blockIdx.x;
    int l = threadIdx.x;          // 0..63, owns u = l+1
    int t_idx = loglen[b] - 1;
    int u_idx = tgtlen[b];
    const float* blankB = blank + (size_t)b * TT * U1;
    const float* cumB   = cum   + (size_t)b * TT * U1;

    float alpha = cumB[l + 1];    // alpha0[u] = cum_emit[b,0,u]
    float a0 = 0.f;               // alpha at u=0
    float afinal = 0.f;
    bool  rec = false;

    if (t_idx == 0) {
        if (l + 1 == u_idx) { afinal = alpha; rec = true; }
        if (u_idx == 0 && l == 0) { afinal = a0; rec = true; }
    }

    // preload rows for t=1: blank row 0, cum row 1
    float blank_u = blankB[l + 1];
    float blank_0 = blankB[0];
    float cum_u   = cumB[U1 + l + 1];

    for (int t = 1; t < TT; ++t) {
        // prefetch rows for t+1
        float nb_u = 0.f, nb_0 = 0.f, nc_u = 0.f;
        if (t + 1 < TT) {
            nb_u = blankB[t * U1 + l + 1];
            nb_0 = blankB[t * U1];
            nc_u = cumB[(t + 1) * U1 + l + 1];
        }

        float f  = alpha + blank_u - cum_u;
        float f0 = a0 + blank_0;            // f at u=0 (cum=0); also new alpha[0]
        #pragma unroll
        for (int off = 1; off < 64; off <<= 1) {
            float o = __shfl_up(f, off);
            if (l >= off) f = logadd(f, o);
        }
        f = logadd(f, f0);
        alpha = cum_u + f;
        a0 = f0;

        if (t == t_idx) {
            if (l + 1 == u_idx) { afinal = alpha; rec = true; }
            if (u_idx == 0 && l == 0) { afinal = a0; rec = true; }
        }

        blank_u = nb_u; blank_0 = nb_0; cum_u = nc_u;
    }

    if (rec) {
        float fb = blankB[t_idx * U1 + u_idx];
        costs[b] = -(afinal + fb);
    }
}

// Kernel 4: mean of the 8 per-batch costs.
__global__ void k_mean(const float* __restrict__ costs, float* __restrict__ out) {
    if (threadIdx.x == 0) {
        float s = 0.f;
        #pragma unroll
        for (int i = 0; i < BB; ++i) s += costs[i];
        out[0] = s / (float)BB;
    }
}

extern "C" void kernel_launch(void* const* d_in, const int* in_sizes, int n_in,
                              void* d_out, int out_size, void* d_ws, size_t ws_size,
                              hipStream_t stream) {
    const float* logits  = (const float*)d_in[0];
    const int*   targets = (const int*)d_in[1];
    const int*   loglen  = (const int*)d_in[2];
    const int*   tgtlen  = (const int*)d_in[3];

    float* ws    = (float*)d_ws;
    float* blank = ws;                        // B*T*(U+1) = 133120
    float* emit  = blank + BB * TT * U1;      // B*T*U     = 131072
    float* cum   = emit  + BB * TT * UU;      // B*T*(U+1) = 133120
    float* costs = cum   + BB * TT * U1;      // B         = 8

    const int nrows = BB * TT * U1;           // 133120 waves, 4 waves/block
    k_logsm<<<nrows / 4, 256, 0, stream>>>(logits, targets, blank, emit);
    k_cum<<<(BB * TT) / 4, 256, 0, stream>>>(emit, cum);
    k_scan<<<BB, 64, 0, stream>>>(blank, cum, loglen, tgtlen, costs);
    k_mean<<<1, 64, 0, stream>>>(costs, (float*)d_out);
}

// Round 2
// 100.972 us; speedup vs baseline: 2.1060x; 2.1060x over previous
//
#include <hip/hip_runtime.h>

#define BB 8
#define TT 256
#define UU 64
#define VV 512
#define U1 (UU + 1)

#define LOG2E 1.4426950408889634f
#define LN2   0.6931471805599453f
#define NEG_INF (-__builtin_inff())

// native base-2 transcendentals (v_exp_f32 / v_log_f32)
__device__ __forceinline__ float vexp2(float x) {
    float r; asm("v_exp_f32 %0, %1" : "=v"(r) : "v"(x)); return r;
}
__device__ __forceinline__ float vlog2(float x) {
    float r; asm("v_log_f32 %0, %1" : "=v"(r) : "v"(x)); return r;
}

// logadd in log2 domain: log2(2^a + 2^b)
__device__ __forceinline__ float logadd2(float a, float b) {
    float m = fmaxf(a, b);
    float e = vexp2(-fabsf(a - b));     // b==-inf -> e=0 -> identity
    return m + vlog2(1.0f + e);
}

template<int CTRL, int RMASK>
__device__ __forceinline__ float dpp_mov(float v, float oldv) {
    int r = __builtin_amdgcn_update_dpp(__float_as_int(oldv), __float_as_int(v),
                                        CTRL, RMASK, 0xf, false);
    return __int_as_float(r);
}

// wave64 inclusive logadd-scan via DPP (identity = -inf)
__device__ __forceinline__ float wave_logscan2(float f) {
    f = logadd2(f, dpp_mov<0x111, 0xf>(f, NEG_INF)); // row_shr:1
    f = logadd2(f, dpp_mov<0x112, 0xf>(f, NEG_INF)); // row_shr:2
    f = logadd2(f, dpp_mov<0x114, 0xf>(f, NEG_INF)); // row_shr:4
    f = logadd2(f, dpp_mov<0x118, 0xf>(f, NEG_INF)); // row_shr:8
    f = logadd2(f, dpp_mov<0x142, 0xa>(f, NEG_INF)); // row_bcast:15 -> rows 1,3
    f = logadd2(f, dpp_mov<0x143, 0xc>(f, NEG_INF)); // row_bcast:31 -> rows 2,3
    return f;
}

// wave64 inclusive add-scan via DPP (identity = 0)
__device__ __forceinline__ float wave_addscan(float v) {
    v += dpp_mov<0x111, 0xf>(v, 0.f);
    v += dpp_mov<0x112, 0xf>(v, 0.f);
    v += dpp_mov<0x114, 0xf>(v, 0.f);
    v += dpp_mov<0x118, 0xf>(v, 0.f);
    v += dpp_mov<0x142, 0xa>(v, 0.f);
    v += dpp_mov<0x143, 0xc>(v, 0.f);
    return v;
}

// Kernel 1: per-row log-softmax; extract blank lp and target (emit) lp.
__global__ __launch_bounds__(256) void k_logsm(const float* __restrict__ logits,
                                               const int* __restrict__ targets,
                                               float* __restrict__ blank,
                                               float* __restrict__ emit) {
    int wave = (int)((blockIdx.x * blockDim.x + threadIdx.x) >> 6);
    int lane = threadIdx.x & 63;
    const int nrows = BB * TT * U1;
    if (wave >= nrows) return;
    const float* row = logits + (size_t)wave * VV;
    float4 v0 = *(const float4*)(row + lane * 4);
    float4 v1 = *(const float4*)(row + 256 + lane * 4);
    float m = fmaxf(fmaxf(fmaxf(v0.x, v0.y), fmaxf(v0.z, v0.w)),
                    fmaxf(fmaxf(v1.x, v1.y), fmaxf(v1.z, v1.w)));
    #pragma unroll
    for (int off = 32; off; off >>= 1) m = fmaxf(m, __shfl_xor(m, off));
    float s = __expf(v0.x - m) + __expf(v0.y - m) + __expf(v0.z - m) + __expf(v0.w - m)
            + __expf(v1.x - m) + __expf(v1.y - m) + __expf(v1.z - m) + __expf(v1.w - m);
    #pragma unroll
    for (int off = 32; off; off >>= 1) s += __shfl_xor(s, off);
    float lse = m + __logf(s);

    int u  = wave % U1;
    int bt = wave / U1;
    if (lane == 0) blank[wave] = v0.x - lse;
    if (u < UU) {
        int b = bt / TT;
        int tgt = targets[b * UU + u];           // in [1, V)
        int owner = (tgt & 255) >> 2;
        if (lane == owner) {
            int slot = tgt & 3;
            float x0 = (tgt < 256) ? v0.x : v1.x;
            float x1 = (tgt < 256) ? v0.y : v1.y;
            float x2 = (tgt < 256) ? v0.z : v1.z;
            float x3 = (tgt < 256) ? v0.w : v1.w;
            float val = (slot == 0) ? x0 : (slot == 1) ? x1 : (slot == 2) ? x2 : x3;
            emit[bt * UU + u] = val - lse;
        }
    }
}

// Kernel 2: build cum (natural log), D and z0 (log2 domain) for the scan.
// Wave (b,t): cum_t = addscan(emit row t); if t>=1 also recompute cum_{t-1} and
//   D[b][t-1][l] = (blank[b][t-1][l+1] + cum_{t-1}[l+1] - cum_t[l+1]) * log2(e)
//   z0[b][t-1]   =  blank[b][t-1][0] * log2(e)
__global__ __launch_bounds__(256) void k_prep(const float* __restrict__ emit,
                                              const float* __restrict__ blank,
                                              float* __restrict__ cum,
                                              float* __restrict__ D,
                                              float* __restrict__ z0) {
    int wave = (int)((blockIdx.x * blockDim.x + threadIdx.x) >> 6);
    int l = threadIdx.x & 63;
    if (wave >= BB * TT) return;
    int b = wave >> 8, t = wave & 255;
    float cT = wave_addscan(emit[wave * UU + l]);
    cum[wave * U1 + l + 1] = cT;
    if (l == 0) cum[wave * U1] = 0.f;
    if (t >= 1) {
        float cP = wave_addscan(emit[(wave - 1) * UU + l]);
        float bl = blank[(wave - 1) * U1 + l + 1];
        D[(b * 256 + (t - 1)) * 64 + l] = (bl + cP - cT) * LOG2E;
        if (l == 0) z0[b * 256 + (t - 1)] = blank[(wave - 1) * U1] * LOG2E;
    } else {
        D[(b * 256 + 255) * 64 + l] = 0.f;   // pad step (computed, never recorded)
        if (l == 0) z0[b * 256 + 255] = 0.f;
    }
}

// Kernel 3: per-batch alpha recursion in log2 domain, DPP scan, distance-2 prefetch.
__global__ __launch_bounds__(64) void k_scan(const float* __restrict__ D,
                                             const float* __restrict__ z0,
                                             const float* __restrict__ cum,
                                             const float* __restrict__ blank,
                                             const int* __restrict__ loglen,
                                             const int* __restrict__ tgtlen,
                                             float* __restrict__ costs) {
    int b = blockIdx.x;
    int l = threadIdx.x;                  // owns u = l+1
    int t_idx = loglen[b] - 1;
    int u_idx = tgtlen[b];
    const float* Db = D + (size_t)b * 256 * 64;
    const float* zb = z0 + b * 256;

    float g = 0.f, g0 = 0.f, gsel = 0.f;  // g==0 at t=0; gsel=0 covers t_idx==0

    float rA[4], zA[4], rB[4], zB[4], rC[4], zC[4];

#define LOADG(r_, z_, c_) do { int c__ = (c_);                                  \
        if (c__ < 64) {                                                          \
            r_[0] = Db[(4 * c__ + 0) * 64 + l];                                  \
            r_[1] = Db[(4 * c__ + 1) * 64 + l];                                  \
            r_[2] = Db[(4 * c__ + 2) * 64 + l];                                  \
            r_[3] = Db[(4 * c__ + 3) * 64 + l];                                  \
            *(float4*)z_ = *(const float4*)(zb + 4 * c__);                       \
        } } while (0)

#define STEP4(r_, z_, c_) do { int cbase = 4 * (c_);                             \
        _Pragma("unroll")                                                        \
        for (int i = 0; i < 4; ++i) {                                            \
            float f  = g + r_[i];                                                \
            float f0 = g0 + z_[i];                                               \
            f = wave_logscan2(f);                                                \
            g = logadd2(f, f0);                                                  \
            g0 = f0;                                                             \
            int s = cbase + i;           /* step t = s+1 */                      \
            if (s == t_idx - 1) {                                                \
                if (l == u_idx - 1) gsel = g;                                    \
                if (u_idx == 0 && l == 0) gsel = g0;                             \
            }                                                                    \
        } } while (0)

    LOADG(rA, zA, 0);
    LOADG(rB, zB, 1);
    LOADG(rC, zC, 2);

    // 64 groups of 4 steps (s = 0..255; s=255 is a zero pad). 3x rotation for
    // distance-2 prefetch: each buffer reloaded 2 full groups before next use.
    for (int cc = 0; cc < 21; ++cc) {
        STEP4(rA, zA, 3 * cc + 0);  LOADG(rA, zA, 3 * cc + 3);
        STEP4(rB, zB, 3 * cc + 1);  LOADG(rB, zB, 3 * cc + 4);
        STEP4(rC, zC, 3 * cc + 2);  LOADG(rC, zC, 3 * cc + 5);
    }
    STEP4(rA, zA, 63);

    bool writer = (t_idx == 0 || u_idx == 0) ? (l == 0) : (l == u_idx - 1);
    if (writer) {
        float a  = cum[(b * 256 + t_idx) * U1 + u_idx] + gsel * LN2;
        float fb = blank[(b * 256 + t_idx) * U1 + u_idx];
        costs[b] = -(a + fb);
    }
#undef LOADG
#undef STEP4
}

// Kernel 4: mean of the 8 per-batch costs.
__global__ void k_mean(const float* __restrict__ costs, float* __restrict__ out) {
    if (threadIdx.x == 0) {
        float s = 0.f;
        #pragma unroll
        for (int i = 0; i < BB; ++i) s += costs[i];
        out[0] = s / (float)BB;
    }
}

extern "C" void kernel_launch(void* const* d_in, const int* in_sizes, int n_in,
                              void* d_out, int out_size, void* d_ws, size_t ws_size,
                              hipStream_t stream) {
    const float* logits  = (const float*)d_in[0];
    const int*   targets = (const int*)d_in[1];
    const int*   loglen  = (const int*)d_in[2];
    const int*   tgtlen  = (const int*)d_in[3];

    float* ws    = (float*)d_ws;
    float* blank = ws;                         // B*T*(U+1) = 133120
    float* emit  = blank + BB * TT * U1;       // B*T*U     = 131072
    float* cum   = emit  + BB * TT * UU;       // B*T*(U+1) = 133120
    float* D     = cum   + BB * TT * U1;       // B*256*64  = 131072
    float* z0    = D     + BB * 256 * 64;      // B*256     = 2048
    float* costs = z0    + BB * 256;           // B         = 8

    const int nrows = BB * TT * U1;
    k_logsm<<<nrows / 4, 256, 0, stream>>>(logits, targets, blank, emit);
    k_prep<<<(BB * TT) / 4, 256, 0, stream>>>(emit, blank, cum, D, z0);
    k_scan<<<BB, 64, 0, stream>>>(D, z0, cum, blank, loglen, tgtlen, costs);
    k_mean<<<1, 64, 0, stream>>>(costs, (float*)d_out);
}